// Round 2
// baseline (1189.270 us; speedup 1.0000x reference)
//
#include <hip/hip_runtime.h>
#include <math.h>

// ---------------- problem constants ----------------
#define T_TOK 16384   // B*S tokens
#define HDIM  1024
#define IDIM  2048
#define NEXP  8
#define CAP   16384   // per-expert capacity (each token at most once per expert)

typedef __bf16 bf16x8 __attribute__((ext_vector_type(8)));
typedef float  f32x4  __attribute__((ext_vector_type(4)));
typedef unsigned short us8 __attribute__((ext_vector_type(8)));

__device__ __forceinline__ unsigned short f2bf(float f) {
  unsigned int u = __builtin_bit_cast(unsigned int, f);
  u = (u + 0x7FFFu + ((u >> 16) & 1u)) >> 16;   // RNE
  return (unsigned short)u;
}

__device__ __forceinline__ void gld16(const void* g, void* l) {
  __builtin_amdgcn_global_load_lds(
      (const __attribute__((address_space(1))) void*)(g),
      (__attribute__((address_space(3))) void*)(l), 16, 0, 0);
}

// read 8 consecutive fp32 from LDS, convert to bf16x8 (RNE)
__device__ __forceinline__ bf16x8 cvt8(const float* p) {
  f32x4 lo = *(const f32x4*)p;
  f32x4 hi = *(const f32x4*)(p + 4);
  us8 t;
  t[0] = f2bf(lo[0]); t[1] = f2bf(lo[1]); t[2] = f2bf(lo[2]); t[3] = f2bf(lo[3]);
  t[4] = f2bf(hi[0]); t[5] = f2bf(hi[1]); t[6] = f2bf(hi[2]); t[7] = f2bf(hi[3]);
  return __builtin_bit_cast(bf16x8, t);
}

// ---------------- tiny utility kernels ----------------
__global__ void zero_counts_k(int* counts) {
  if (threadIdx.x < NEXP) counts[threadIdx.x] = 0;
}

__global__ void zero_out_k(float4* out) {   // one float4 per thread, T*H/4 total
  out[blockIdx.x * 256 + threadIdx.x] = float4{0.f, 0.f, 0.f, 0.f};
}

__global__ void report_k(float* out, float v, int n) {  // diagnostic: absmax == ws MB
  int idx = blockIdx.x * blockDim.x + threadIdx.x;
  int stride = gridDim.x * blockDim.x;
  for (int i = idx; i < n; i += stride) out[i] = v;
}

// ---------------- fp32 -> bf16 conversion (grid-stride, float4) ----------------
__global__ void cvt_bf16_k(const float* __restrict__ src, unsigned short* __restrict__ dst, int n4) {
  int idx = blockIdx.x * blockDim.x + threadIdx.x;
  int stride = gridDim.x * blockDim.x;
  for (int i = idx; i < n4; i += stride) {
    float4 v = ((const float4*)src)[i];
    ushort4 o;
    o.x = f2bf(v.x); o.y = f2bf(v.y); o.z = f2bf(v.z); o.w = f2bf(v.w);
    ((ushort4*)dst)[i] = o;
  }
}

// ---------------- routing: fp32 logits, top-2, softmax, slot assignment ----------------
__global__ void route_k(const float* __restrict__ x, const float* __restrict__ wg,
                        int* counts, int* etok, float* tgate) {
  __shared__ __align__(16) float wgl[NEXP * HDIM];   // 32 KB
  int tid = threadIdx.x;
  for (int i = tid; i < NEXP * HDIM / 4; i += 256)
    ((float4*)wgl)[i] = ((const float4*)wg)[i];
  __syncthreads();

  int wave = tid >> 6, lane = tid & 63;
  int t = blockIdx.x * 4 + wave;

  float accv[NEXP];
#pragma unroll
  for (int e = 0; e < NEXP; e++) accv[e] = 0.f;
  const float* xr = x + (size_t)t * HDIM;
#pragma unroll 4
  for (int j = 0; j < HDIM / 64; j++) {
    float xv = xr[lane + j * 64];
#pragma unroll
    for (int e = 0; e < NEXP; e++) accv[e] += xv * wgl[e * HDIM + lane + j * 64];
  }
#pragma unroll
  for (int off = 1; off < 64; off <<= 1) {
#pragma unroll
    for (int e = 0; e < NEXP; e++) accv[e] += __shfl_xor(accv[e], off, 64);
  }

  if (lane == 0) {
    int e0 = 0; float v0 = accv[0];
#pragma unroll
    for (int e = 1; e < NEXP; e++) if (accv[e] > v0) { v0 = accv[e]; e0 = e; }
    int e1 = -1; float v1 = -3.4e38f;
#pragma unroll
    for (int e = 0; e < NEXP; e++) if (e != e0 && accv[e] > v1) { v1 = accv[e]; e1 = e; }
    float ex = expf(v1 - v0);
    float g0 = 1.f / (1.f + ex);
    float g1 = ex / (1.f + ex);
    int s0 = atomicAdd(&counts[e0], 1);
    etok[e0 * CAP + s0] = t * 2;
    int s1 = atomicAdd(&counts[e1], 1);
    etok[e1 * CAP + s1] = t * 2 + 1;
    tgate[t * 2] = g0;
    tgate[t * 2 + 1] = g1;
  }
}

// ---------------- grouped GEMM (128x128x32 tile, m97 recipe) ----------------
// STAGE 1: hmid[code][n] = gelu( x[code>>1][:] . w_fc[e][n][:] + b_fc[e][n] )   K=HDIM, N=IDIM
// STAGE 2: atomicAdd(out[code>>1][n], tgate[code] * (hmid[code][:] . w_proj[e][n][:] + b_proj[e][n]))
// A32/B32: operand held in global as fp32; staged to LDS as fp32, converted at fragment read.
template <int STAGE, int K, int N, bool A32, bool B32>
__global__ __launch_bounds__(256)
void gemm_k(const void* __restrict__ Ap_, const void* __restrict__ Wp_,
            const float* __restrict__ bias, unsigned short* __restrict__ hmid,
            float* __restrict__ out, const float* __restrict__ tgate,
            const int* __restrict__ counts, const int* __restrict__ etok) {
  constexpr int NT = N / 128;
  constexpr int ASZ = A32 ? 16384 : 8192;   // bytes: 128 rows x 32 elems
  constexpr int BSZ = B32 ? 16384 : 8192;
  __shared__ __align__(16) char smem[ASZ + BSZ];
  char* As = smem;
  char* Bs = smem + ASZ;

  int e  = blockIdx.x / (128 * NT);
  int bi = blockIdx.x % (128 * NT);
  int rt = bi / NT, ct = bi % NT;
  int cnt = counts[e];
  if (rt * 128 >= cnt) return;

  int tid = threadIdx.x;
  int lane = tid & 63, wv = tid >> 6;
  int wr = wv >> 1, wc = wv & 1;          // 2x2 wave grid, 64x64 per wave
  int quad = lane >> 4, ml = lane & 15;

  // ---- staging pointers (LDS byte offset is q*4096 + tid*16 for both elt widths) ----
  const char* aptr[4];
  if constexpr (A32) {
    int srow = tid >> 3, seg = tid & 7;   // 32 rows per quarter, 8x16B per row
    const float* Af = (const float*)Ap_;
#pragma unroll
    for (int q = 0; q < 4; q++) {
      int r = rt * 128 + q * 32 + srow;
      int code = etok[e * CAP + (r < cnt ? r : cnt - 1)];
      int row = (STAGE == 1) ? (code >> 1) : code;
      aptr[q] = (const char*)(Af + (size_t)row * K + seg * 4);
    }
  } else {
    int srow = tid >> 2, seg = tid & 3;   // 64 rows per half, 4x16B per row
    const unsigned short* Ab = (const unsigned short*)Ap_;
#pragma unroll
    for (int q = 0; q < 2; q++) {
      int r = rt * 128 + q * 64 + srow;
      int code = etok[e * CAP + (r < cnt ? r : cnt - 1)];
      int row = (STAGE == 1) ? (code >> 1) : code;
      aptr[q] = (const char*)(Ab + (size_t)row * K + seg * 8);
    }
  }
  const char* bptr[4];
  if constexpr (B32) {
    int srow = tid >> 3, seg = tid & 7;
    const float* Wf = (const float*)Wp_;
#pragma unroll
    for (int q = 0; q < 4; q++)
      bptr[q] = (const char*)(Wf + ((size_t)e * N + ct * 128 + q * 32 + srow) * K + seg * 4);
  } else {
    int srow = tid >> 2, seg = tid & 3;
    const unsigned short* Wb = (const unsigned short*)Wp_;
#pragma unroll
    for (int q = 0; q < 2; q++)
      bptr[q] = (const char*)(Wb + ((size_t)e * N + ct * 128 + q * 64 + srow) * K + seg * 8);
  }

  f32x4 acc[4][4] = {};

  for (int k0 = 0; k0 < K; k0 += 32) {
    size_t aoff = (size_t)k0 * (A32 ? 4 : 2);
    size_t boff = (size_t)k0 * (B32 ? 4 : 2);
    if constexpr (A32) {
#pragma unroll
      for (int q = 0; q < 4; q++) gld16(aptr[q] + aoff, As + q * 4096 + tid * 16);
    } else {
#pragma unroll
      for (int q = 0; q < 2; q++) gld16(aptr[q] + aoff, As + q * 4096 + tid * 16);
    }
    if constexpr (B32) {
#pragma unroll
      for (int q = 0; q < 4; q++) gld16(bptr[q] + boff, Bs + q * 4096 + tid * 16);
    } else {
#pragma unroll
      for (int q = 0; q < 2; q++) gld16(bptr[q] + boff, Bs + q * 4096 + tid * 16);
    }
    __syncthreads();

    bf16x8 af[4], bfr[4];
#pragma unroll
    for (int mi = 0; mi < 4; mi++) {
      int row = wr * 64 + mi * 16 + ml;
      if constexpr (A32) af[mi] = cvt8((const float*)As + row * 32 + quad * 8);
      else af[mi] = __builtin_bit_cast(bf16x8, *(const us8*)((const unsigned short*)As + row * 32 + quad * 8));
    }
#pragma unroll
    for (int ni = 0; ni < 4; ni++) {
      int row = wc * 64 + ni * 16 + ml;
      if constexpr (B32) bfr[ni] = cvt8((const float*)Bs + row * 32 + quad * 8);
      else bfr[ni] = __builtin_bit_cast(bf16x8, *(const us8*)((const unsigned short*)Bs + row * 32 + quad * 8));
    }
#pragma unroll
    for (int mi = 0; mi < 4; mi++)
#pragma unroll
      for (int ni = 0; ni < 4; ni++)
        acc[mi][ni] = __builtin_amdgcn_mfma_f32_16x16x32_bf16(af[mi], bfr[ni], acc[mi][ni], 0, 0, 0);
    __syncthreads();
  }

  // epilogue: C/D layout (verified m89): col = lane&15, row = quad*4 + reg
#pragma unroll
  for (int mi = 0; mi < 4; mi++) {
    int ms[4], codes[4];
#pragma unroll
    for (int r = 0; r < 4; r++) {
      ms[r] = rt * 128 + wr * 64 + mi * 16 + quad * 4 + r;
      codes[r] = etok[e * CAP + (ms[r] < cnt ? ms[r] : 0)];
    }
#pragma unroll
    for (int ni = 0; ni < 4; ni++) {
      int n = ct * 128 + wc * 64 + ni * 16 + ml;
      float bv = bias[e * N + n];
#pragma unroll
      for (int r = 0; r < 4; r++) {
        if (ms[r] < cnt) {
          float v = acc[mi][ni][r] + bv;
          if (STAGE == 1) {
            v = 0.5f * v * (1.0f + erff(v * 0.70710678118654752f));  // exact gelu
            hmid[(size_t)codes[r] * IDIM + n] = f2bf(v);
          } else {
            float g = tgate[codes[r]];
            atomicAdd(&out[(size_t)(codes[r] >> 1) * HDIM + n], g * v);
          }
        }
      }
    }
  }
}

// ---------------- launch ----------------
extern "C" void kernel_launch(void* const* d_in, const int* in_sizes, int n_in,
                              void* d_out, int out_size, void* d_ws, size_t ws_size,
                              hipStream_t stream) {
  const float* x     = (const float*)d_in[0];  // [T, H]
  const float* wg    = (const float*)d_in[1];  // [E, H]
  const float* wfc   = (const float*)d_in[2];  // [E, I, H]
  const float* bfc   = (const float*)d_in[3];  // [E, I]
  const float* wproj = (const float*)d_in[4];  // [E, H, I]
  const float* bproj = (const float*)d_in[5];  // [E, H]
  float* out = (float*)d_out;

  // workspace layout (bytes)
  char* ws = (char*)d_ws;
  size_t off = 0;
  int* counts = (int*)(ws + off);    off += 4096;
  int* etok   = (int*)(ws + off);    off += (size_t)NEXP * CAP * 4;    // 512 KB
  float* tgate = (float*)(ws + off); off += (size_t)T_TOK * 2 * 4;     // 128 KB
  unsigned short* hmid = (unsigned short*)(ws + off);
  off += (size_t)T_TOK * 2 * IDIM * 2;                                  // 134 MB
  size_t lean_need = off;                                               // ~135 MB
  unsigned short* xbf = (unsigned short*)(ws + off);
  size_t off2 = off + (size_t)T_TOK * HDIM * 2;                         // +33.5 MB
  unsigned short* wfcbf = (unsigned short*)(ws + off2);
  off2 += (size_t)NEXP * IDIM * HDIM * 2;                               // +33.5 MB
  unsigned short* wprojbf = (unsigned short*)(ws + off2);
  off2 += (size_t)NEXP * HDIM * IDIM * 2;                               // +33.5 MB
  size_t full_need = off2;                                              // ~236 MB

  if (ws_size < lean_need) {
    // Diagnostic: can't fit the mandatory intermediate. Report ws MB via absmax.
    report_k<<<256, 256, 0, stream>>>(out, (float)(ws_size >> 20), T_TOK * HDIM);
    return;
  }

  zero_counts_k<<<1, 64, 0, stream>>>(counts);
  route_k<<<T_TOK / 4, 256, 0, stream>>>(x, wg, counts, etok, tgate);
  zero_out_k<<<T_TOK * HDIM / 1024, 256, 0, stream>>>((float4*)out);

  if (ws_size >= full_need) {
    // fast path: pre-convert operands to bf16
    cvt_bf16_k<<<4096, 256, 0, stream>>>(x,     xbf,     T_TOK * HDIM / 4);
    cvt_bf16_k<<<4096, 256, 0, stream>>>(wfc,   wfcbf,   NEXP * IDIM * HDIM / 4);
    cvt_bf16_k<<<4096, 256, 0, stream>>>(wproj, wprojbf, NEXP * HDIM * IDIM / 4);
    gemm_k<1, HDIM, IDIM, false, false><<<NEXP * 128 * (IDIM / 128), 256, 0, stream>>>(
        xbf, wfcbf, bfc, hmid, out, tgate, counts, etok);
    gemm_k<2, IDIM, HDIM, false, false><<<NEXP * 128 * (HDIM / 128), 256, 0, stream>>>(
        hmid, wprojbf, bproj, hmid, out, tgate, counts, etok);
  } else {
    // lean path: stage fp32 operands, convert at fragment read
    gemm_k<1, HDIM, IDIM, true, true><<<NEXP * 128 * (IDIM / 128), 256, 0, stream>>>(
        x, wfc, bfc, hmid, out, tgate, counts, etok);
    gemm_k<2, IDIM, HDIM, false, true><<<NEXP * 128 * (HDIM / 128), 256, 0, stream>>>(
        hmid, wproj, bproj, hmid, out, tgate, counts, etok);
  }
}

// Round 3
// 735.300 us; speedup vs baseline: 1.6174x; 1.6174x over previous
//
#include <hip/hip_runtime.h>
#include <math.h>

// ---------------- problem constants ----------------
#define T_TOK 16384   // B*S tokens
#define HDIM  1024
#define IDIM  2048
#define NEXP  8
#define CAP   16384   // per-expert capacity (each token at most once per expert)

typedef __bf16 bf16x8 __attribute__((ext_vector_type(8)));
typedef float  f32x4  __attribute__((ext_vector_type(4)));
typedef unsigned short us8 __attribute__((ext_vector_type(8)));

__device__ __forceinline__ unsigned short f2bf(float f) {
  unsigned int u = __builtin_bit_cast(unsigned int, f);
  u = (u + 0x7FFFu + ((u >> 16) & 1u)) >> 16;   // RNE
  return (unsigned short)u;
}

__device__ __forceinline__ float bf2f(unsigned short u) {
  return __builtin_bit_cast(float, (unsigned int)u << 16);
}

__device__ __forceinline__ void gld16(const void* g, void* l) {
  __builtin_amdgcn_global_load_lds(
      (const __attribute__((address_space(1))) void*)(g),
      (__attribute__((address_space(3))) void*)(l), 16, 0, 0);
}

// read 8 consecutive fp32 from LDS, convert to bf16x8 (RNE)
__device__ __forceinline__ bf16x8 cvt8(const float* p) {
  f32x4 lo = *(const f32x4*)p;
  f32x4 hi = *(const f32x4*)(p + 4);
  us8 t;
  t[0] = f2bf(lo[0]); t[1] = f2bf(lo[1]); t[2] = f2bf(lo[2]); t[3] = f2bf(lo[3]);
  t[4] = f2bf(hi[0]); t[5] = f2bf(hi[1]); t[6] = f2bf(hi[2]); t[7] = f2bf(hi[3]);
  return __builtin_bit_cast(bf16x8, t);
}

// ---------------- tiny utility kernels ----------------
__global__ void zero_out_k(float4* out) {   // one float4 per thread
  out[blockIdx.x * 256 + threadIdx.x] = float4{0.f, 0.f, 0.f, 0.f};
}

__global__ void report_k(float* out, float v, int n) {  // diagnostic: absmax == ws MB
  int idx = blockIdx.x * blockDim.x + threadIdx.x;
  int stride = gridDim.x * blockDim.x;
  for (int i = idx; i < n; i += stride) out[i] = v;
}

// ---------------- fp32 -> bf16 conversion (grid-stride, float4) ----------------
__global__ void cvt_bf16_k(const float* __restrict__ src, unsigned short* __restrict__ dst, int n4) {
  int idx = blockIdx.x * blockDim.x + threadIdx.x;
  int stride = gridDim.x * blockDim.x;
  for (int i = idx; i < n4; i += stride) {
    float4 v = ((const float4*)src)[i];
    ushort4 o;
    o.x = f2bf(v.x); o.y = f2bf(v.y); o.z = f2bf(v.z); o.w = f2bf(v.w);
    ((ushort4*)dst)[i] = o;
  }
}

// ---------------- routing pass 1: fp32 logits, top-2, softmax (NO atomics) ----------------
__global__ void route1_k(const float* __restrict__ x, const float* __restrict__ wg,
                         int* __restrict__ echoice, float* __restrict__ tgate) {
  __shared__ __align__(16) float wgl[NEXP * HDIM];   // 32 KB
  int tid = threadIdx.x;
  for (int i = tid; i < NEXP * HDIM / 4; i += 256)
    ((float4*)wgl)[i] = ((const float4*)wg)[i];
  __syncthreads();

  int wave = tid >> 6, lane = tid & 63;
  int t = blockIdx.x * 4 + wave;

  float accv[NEXP];
#pragma unroll
  for (int e = 0; e < NEXP; e++) accv[e] = 0.f;
  const float* xr = x + (size_t)t * HDIM;
#pragma unroll 4
  for (int j = 0; j < HDIM / 64; j++) {
    float xv = xr[lane + j * 64];
#pragma unroll
    for (int e = 0; e < NEXP; e++) accv[e] += xv * wgl[e * HDIM + lane + j * 64];
  }
#pragma unroll
  for (int off = 1; off < 64; off <<= 1) {
#pragma unroll
    for (int e = 0; e < NEXP; e++) accv[e] += __shfl_xor(accv[e], off, 64);
  }

  if (lane == 0) {
    int e0 = 0; float v0 = accv[0];
#pragma unroll
    for (int e = 1; e < NEXP; e++) if (accv[e] > v0) { v0 = accv[e]; e0 = e; }
    int e1 = -1; float v1 = -3.4e38f;
#pragma unroll
    for (int e = 0; e < NEXP; e++) if (e != e0 && accv[e] > v1) { v1 = accv[e]; e1 = e; }
    float ex = expf(v1 - v0);
    echoice[t] = e0 | (e1 << 8);
    tgate[t * 2]     = 1.f / (1.f + ex);
    tgate[t * 2 + 1] = ex / (1.f + ex);
  }
}

// ---------------- routing pass 2: deterministic per-expert compaction ----------------
// one block per expert; ballot/popcount prefix scan; zero global atomics.
__global__ void route2_k(const int* __restrict__ echoice, int* __restrict__ counts,
                         int* __restrict__ etok) {
  int E = blockIdx.x;
  int tid = threadIdx.x, lane = tid & 63, wv = tid >> 6;
  __shared__ int base;
  __shared__ int wsum[4];
  if (tid == 0) base = 0;
  __syncthreads();
  for (int t0 = 0; t0 < T_TOK; t0 += 256) {
    int t = t0 + tid;
    int ec = echoice[t];
    int e0 = ec & 255, e1 = (ec >> 8) & 255;
    bool m = (e0 == E) | (e1 == E);
    int code = t * 2 + (e1 == E ? 1 : 0);
    unsigned long long mask = __ballot(m);
    if (lane == 0) wsum[wv] = __popcll(mask);
    int lpre = __popcll(mask & ((1ull << lane) - 1ull));
    __syncthreads();
    int wbase = 0;
#pragma unroll
    for (int w = 0; w < 4; w++) if (w < wv) wbase += wsum[w];
    int total = wsum[0] + wsum[1] + wsum[2] + wsum[3];
    if (m) etok[E * CAP + base + wbase + lpre] = code;
    __syncthreads();
    if (tid == 0) base += total;
    __syncthreads();
  }
  if (tid == 0) counts[E] = base;
}

// ---------------- grouped GEMM (128x128x32 tile, m97 recipe) ----------------
// STAGE 1: hmid[code][n] = gelu( x[code>>1][:] . w_fc[e][n][:] + b_fc[e][n] )   K=HDIM, N=IDIM
// STAGE 2, YATOM=0: ybf[code][n] = bf16( hmid[code][:] . w_proj[e][n][:] + b_proj[e][n] )
// STAGE 2, YATOM=1: atomicAdd(out[code>>1][n], tgate[code] * (...))
template <int STAGE, int K, int N, bool A32, bool B32, bool YATOM>
__global__ __launch_bounds__(256)
void gemm_k(const void* __restrict__ Ap_, const void* __restrict__ Wp_,
            const float* __restrict__ bias, unsigned short* __restrict__ hmid,
            unsigned short* __restrict__ ybf, float* __restrict__ out,
            const float* __restrict__ tgate,
            const int* __restrict__ counts, const int* __restrict__ etok) {
  constexpr int NT = N / 128;
  constexpr int ASZ = A32 ? 16384 : 8192;   // bytes: 128 rows x 32 elems
  constexpr int BSZ = B32 ? 16384 : 8192;
  __shared__ __align__(16) char smem[ASZ + BSZ];
  char* As = smem;
  char* Bs = smem + ASZ;

  int e  = blockIdx.x / (128 * NT);
  int bi = blockIdx.x % (128 * NT);
  int rt = bi / NT, ct = bi % NT;
  int cnt = counts[e];
  if (rt * 128 >= cnt) return;

  int tid = threadIdx.x;
  int lane = tid & 63, wv = tid >> 6;
  int wr = wv >> 1, wc = wv & 1;          // 2x2 wave grid, 64x64 per wave
  int quad = lane >> 4, ml = lane & 15;

  // ---- staging pointers (LDS byte offset is q*4096 + tid*16 for both widths) ----
  const char* aptr[4];
  if constexpr (A32) {
    int srow = tid >> 3, seg = tid & 7;   // 32 rows per quarter, 8x16B per row
    const float* Af = (const float*)Ap_;
#pragma unroll
    for (int q = 0; q < 4; q++) {
      int r = rt * 128 + q * 32 + srow;
      int code = etok[e * CAP + (r < cnt ? r : cnt - 1)];
      int row = (STAGE == 1) ? (code >> 1) : code;
      aptr[q] = (const char*)(Af + (size_t)row * K + seg * 4);
    }
  } else {
    int srow = tid >> 2, seg = tid & 3;   // 64 rows per half, 4x16B per row
    const unsigned short* Ab = (const unsigned short*)Ap_;
#pragma unroll
    for (int q = 0; q < 2; q++) {
      int r = rt * 128 + q * 64 + srow;
      int code = etok[e * CAP + (r < cnt ? r : cnt - 1)];
      int row = (STAGE == 1) ? (code >> 1) : code;
      aptr[q] = (const char*)(Ab + (size_t)row * K + seg * 8);
    }
  }
  const char* bptr[4];
  if constexpr (B32) {
    int srow = tid >> 3, seg = tid & 7;
    const float* Wf = (const float*)Wp_;
#pragma unroll
    for (int q = 0; q < 4; q++)
      bptr[q] = (const char*)(Wf + ((size_t)e * N + ct * 128 + q * 32 + srow) * K + seg * 4);
  } else {
    int srow = tid >> 2, seg = tid & 3;
    const unsigned short* Wb = (const unsigned short*)Wp_;
#pragma unroll
    for (int q = 0; q < 2; q++)
      bptr[q] = (const char*)(Wb + ((size_t)e * N + ct * 128 + q * 64 + srow) * K + seg * 8);
  }

  f32x4 acc[4][4] = {};

  for (int k0 = 0; k0 < K; k0 += 32) {
    size_t aoff = (size_t)k0 * (A32 ? 4 : 2);
    size_t boff = (size_t)k0 * (B32 ? 4 : 2);
    if constexpr (A32) {
#pragma unroll
      for (int q = 0; q < 4; q++) gld16(aptr[q] + aoff, As + q * 4096 + tid * 16);
    } else {
#pragma unroll
      for (int q = 0; q < 2; q++) gld16(aptr[q] + aoff, As + q * 4096 + tid * 16);
    }
    if constexpr (B32) {
#pragma unroll
      for (int q = 0; q < 4; q++) gld16(bptr[q] + boff, Bs + q * 4096 + tid * 16);
    } else {
#pragma unroll
      for (int q = 0; q < 2; q++) gld16(bptr[q] + boff, Bs + q * 4096 + tid * 16);
    }
    __syncthreads();

    bf16x8 af[4], bfr[4];
#pragma unroll
    for (int mi = 0; mi < 4; mi++) {
      int row = wr * 64 + mi * 16 + ml;
      if constexpr (A32) af[mi] = cvt8((const float*)As + row * 32 + quad * 8);
      else af[mi] = __builtin_bit_cast(bf16x8, *(const us8*)((const unsigned short*)As + row * 32 + quad * 8));
    }
#pragma unroll
    for (int ni = 0; ni < 4; ni++) {
      int row = wc * 64 + ni * 16 + ml;
      if constexpr (B32) bfr[ni] = cvt8((const float*)Bs + row * 32 + quad * 8);
      else bfr[ni] = __builtin_bit_cast(bf16x8, *(const us8*)((const unsigned short*)Bs + row * 32 + quad * 8));
    }
#pragma unroll
    for (int mi = 0; mi < 4; mi++)
#pragma unroll
      for (int ni = 0; ni < 4; ni++)
        acc[mi][ni] = __builtin_amdgcn_mfma_f32_16x16x32_bf16(af[mi], bfr[ni], acc[mi][ni], 0, 0, 0);
    __syncthreads();
  }

  // epilogue: C/D layout (verified m89): col = lane&15, row = quad*4 + reg
#pragma unroll
  for (int mi = 0; mi < 4; mi++) {
    int ms[4], codes[4];
#pragma unroll
    for (int r = 0; r < 4; r++) {
      ms[r] = rt * 128 + wr * 64 + mi * 16 + quad * 4 + r;
      codes[r] = etok[e * CAP + (ms[r] < cnt ? ms[r] : 0)];
    }
#pragma unroll
    for (int ni = 0; ni < 4; ni++) {
      int n = ct * 128 + wc * 64 + ni * 16 + ml;
      float bv = bias[e * N + n];
#pragma unroll
      for (int r = 0; r < 4; r++) {
        if (ms[r] < cnt) {
          float v = acc[mi][ni][r] + bv;
          if (STAGE == 1) {
            v = 0.5f * v * (1.0f + erff(v * 0.70710678118654752f));  // exact gelu
            hmid[(size_t)codes[r] * IDIM + n] = f2bf(v);
          } else if (YATOM) {
            atomicAdd(&out[(size_t)(codes[r] >> 1) * HDIM + n], tgate[codes[r]] * v);
          } else {
            ybf[(size_t)codes[r] * HDIM + n] = f2bf(v);
          }
        }
      }
    }
  }
}

// ---------------- combine (fast path): out[t] = g0*y[2t] + g1*y[2t+1], y is bf16 ----------------
__global__ void combine_k(const unsigned short* __restrict__ y, const float* __restrict__ tgate,
                          float* __restrict__ out) {
  int idx = blockIdx.x * 256 + threadIdx.x;  // T*H/8 threads
  int t = idx >> 7;                          // H/8 = 128 chunks per token
  int c = idx & 127;
  float g0 = tgate[t * 2], g1 = tgate[t * 2 + 1];
  us8 a = *(const us8*)(y + ((size_t)(t * 2) * HDIM) + c * 8);
  us8 b = *(const us8*)(y + ((size_t)(t * 2 + 1) * HDIM) + c * 8);
  float o[8];
#pragma unroll
  for (int i = 0; i < 8; i++) o[i] = g0 * bf2f(a[i]) + g1 * bf2f(b[i]);
  float4* op = (float4*)(out + (size_t)t * HDIM + c * 8);
  op[0] = float4{o[0], o[1], o[2], o[3]};
  op[1] = float4{o[4], o[5], o[6], o[7]};
}

// ---------------- launch ----------------
extern "C" void kernel_launch(void* const* d_in, const int* in_sizes, int n_in,
                              void* d_out, int out_size, void* d_ws, size_t ws_size,
                              hipStream_t stream) {
  const float* x     = (const float*)d_in[0];  // [T, H]
  const float* wg    = (const float*)d_in[1];  // [E, H]
  const float* wfc   = (const float*)d_in[2];  // [E, I, H]
  const float* bfc   = (const float*)d_in[3];  // [E, I]
  const float* wproj = (const float*)d_in[4];  // [E, H, I]
  const float* bproj = (const float*)d_in[5];  // [E, H]
  float* out = (float*)d_out;

  // workspace layout (bytes)
  char* ws = (char*)d_ws;
  size_t off = 0;
  int* counts  = (int*)(ws + off);   off += 4096;
  int* echoice = (int*)(ws + off);   off += (size_t)T_TOK * 4;          // 64 KB
  int* etok    = (int*)(ws + off);   off += (size_t)NEXP * CAP * 4;     // 512 KB
  float* tgate = (float*)(ws + off); off += (size_t)T_TOK * 2 * 4;      // 128 KB
  unsigned short* hmid = (unsigned short*)(ws + off);
  off += (size_t)T_TOK * 2 * IDIM * 2;                                  // 134 MB
  size_t lean_need = off;                                               // ~135 MB
  // fast-path extras: xbf(33.5) + wfcbf(33.5) + wprojbf(33.5)
  unsigned short* xbf = (unsigned short*)(ws + off);
  size_t off2 = off + (size_t)T_TOK * HDIM * 2;
  unsigned short* wfcbf = (unsigned short*)(ws + off2);
  off2 += (size_t)NEXP * IDIM * HDIM * 2;
  unsigned short* wprojbf = (unsigned short*)(ws + off2);
  off2 += (size_t)NEXP * HDIM * IDIM * 2;
  size_t full_need = off2;                                              // ~236 MB
  // ybf (67 MB, bf16 [2T, H]) aliases xbf+wfcbf — both dead after GEMM1.
  unsigned short* ybf = xbf;

  if (ws_size < lean_need) {
    report_k<<<256, 256, 0, stream>>>(out, (float)(ws_size >> 20), T_TOK * HDIM);
    return;
  }

  route1_k<<<T_TOK / 4, 256, 0, stream>>>(x, wg, echoice, tgate);
  route2_k<<<NEXP, 256, 0, stream>>>(echoice, counts, etok);

  if (ws_size >= full_need) {
    // fast path: pre-convert operands to bf16; non-atomic epilogue via ybf + combine
    cvt_bf16_k<<<4096, 256, 0, stream>>>(x,     xbf,     T_TOK * HDIM / 4);
    cvt_bf16_k<<<4096, 256, 0, stream>>>(wfc,   wfcbf,   NEXP * IDIM * HDIM / 4);
    cvt_bf16_k<<<4096, 256, 0, stream>>>(wproj, wprojbf, NEXP * HDIM * IDIM / 4);
    gemm_k<1, HDIM, IDIM, false, false, false><<<NEXP * 128 * (IDIM / 128), 256, 0, stream>>>(
        xbf, wfcbf, bfc, hmid, ybf, out, tgate, counts, etok);
    gemm_k<2, IDIM, HDIM, false, false, false><<<NEXP * 128 * (HDIM / 128), 256, 0, stream>>>(
        hmid, wprojbf, bproj, hmid, ybf, out, tgate, counts, etok);
    combine_k<<<T_TOK * HDIM / 8 / 256, 256, 0, stream>>>(ybf, tgate, out);
  } else {
    // lean path: stage fp32 operands, convert at fragment read; atomic epilogue
    zero_out_k<<<T_TOK * HDIM / 1024, 256, 0, stream>>>((float4*)out);
    gemm_k<1, HDIM, IDIM, true, true, true><<<NEXP * 128 * (IDIM / 128), 256, 0, stream>>>(
        x, wfc, bfc, hmid, ybf, out, tgate, counts, etok);
    gemm_k<2, IDIM, HDIM, false, true, true><<<NEXP * 128 * (HDIM / 128), 256, 0, stream>>>(
        hmid, wproj, bproj, hmid, ybf, out, tgate, counts, etok);
  }
}